// Round 8
// baseline (406.640 us; speedup 1.0000x reference)
//
#include <hip/hip_runtime.h>

typedef __bf16 bf16x8 __attribute__((ext_vector_type(8)));
typedef float  f32x4  __attribute__((ext_vector_type(4)));

#define LDS_AS(p)  ((__attribute__((address_space(3))) void*)(p))
#define GLB_AS(p)  ((const __attribute__((address_space(1))) void*)(p))

__device__ __forceinline__ unsigned short f2bf(float f){
  unsigned u = __float_as_uint(f);
  return (unsigned short)((u + 0x7fffu + ((u >> 16) & 1u)) >> 16);  // RNE
}

// ---------------- prep: fuse Wk|Wv -> Wt bf16 [1024 fused cols][512 d]; zero accg+bar+rows
__global__ void prep_kernel(const float* __restrict__ Wk, const float* __restrict__ Wv,
                            unsigned short* __restrict__ Wt, float* __restrict__ accg){
  int i = blockIdx.x * 256 + threadIdx.x;          // 0..524287
  if (i < 8192) accg[i] = 0.f;                     // accg[4096] + bar[2] + rows[2048] + pad
  int f  = i >> 9, d = i & 511;
  int gf = f >> 4, t = f & 15;
  int c  = (gf >> 1) * 16 + t;                     // col in [0,512) == h*64+hd
  const float* W = (gf & 1) ? Wv : Wk;
  int h = c >> 6, hd = c & 63;
  Wt[i] = f2bf(W[(h * 512 + d) * 64 + hd]);
}

// ---------------- grid-wide barrier: counter, device-scope atomics (G16 mechanism).
// Safe only because grid(512) <= guaranteed-resident capacity (2 blocks/CU x 256 CU).
__device__ __forceinline__ void gridbar(int* ctr, int target){
  __threadfence();                                 // release my global writes
  __syncthreads();
  if (threadIdx.x == 0){
    __hip_atomic_fetch_add(ctr, 1, __ATOMIC_ACQ_REL, __HIP_MEMORY_SCOPE_AGENT);
    while (__hip_atomic_load(ctr, __ATOMIC_ACQUIRE, __HIP_MEMORY_SCOPE_AGENT) < target)
      __builtin_amdgcn_s_sleep(16);
  }
  __syncthreads();
  (void)__hip_atomic_load(ctr, __ATOMIC_ACQUIRE, __HIP_MEMORY_SCOPE_AGENT); // per-wave acquire
}

// ---------------- fused: P1 4x(R2-exact 128x128 GEMM tile + atomics) | bar |
// P2 finalize (O=KV/Ksum, O@Wo+bo, gelu -> rows) | bar | P3 broadcast out.
__global__ __launch_bounds__(256, 2) void fused_kernel(const float* __restrict__ x,
    const unsigned short* __restrict__ Wt, const float* __restrict__ bk,
    const float* __restrict__ bv, float* __restrict__ accg,
    const float* __restrict__ Wo, const float* __restrict__ bo,
    int* __restrict__ bar, float* __restrict__ rowsg, float4* __restrict__ out){
  __shared__ __align__(16) unsigned short As[128 * 64];  // 16 KB
  __shared__ __align__(16) unsigned short Bs[128 * 64];  // 16 KB

  int bid = blockIdx.x;
  int tid = threadIdx.x;
  int l = tid & 63, w = tid >> 6;
  int wr = w >> 1, wc = w & 1;
  int swz = (bid & 7) * 64 + (bid >> 3);           // XCD swizzle (512 % 8 == 0)

  // ============ P1: four sequential tiles; panel's 8 bcol-blocks share one XCD ============
  for (int pi = 0; pi < 4; ++pi){
    int wg    = pi * 512 + swz;
    int panel = wg >> 3, bcol = wg & 7;
    int row0  = panel << 7;
    int n     = panel >> 6;

    const f32x4 vz = {0.f, 0.f, 0.f, 0.f};
    f32x4 acc[4][4];
    #pragma unroll
    for (int m = 0; m < 4; ++m)
      #pragma unroll
      for (int q = 0; q < 4; ++q) acc[m][q] = vz;

    int rA = w * 32 + (l >> 3);
    int cc = l & 7;
    const float* xg = x + (size_t)(row0 + rA) * 512 + cc * 8;

    float4 fA[4][2];
    #pragma unroll
    for (int j = 0; j < 4; ++j){                   // prologue: kt=0 A loads
      const float* g = xg + (size_t)j * 8 * 512;
      fA[j][0] = *(const float4*)g;
      fA[j][1] = *(const float4*)(g + 4);
    }

    for (int kt = 0; kt < 8; ++kt){
      if (kt + pi) __syncthreads();                // prev LDS reads (incl. prev pi) done
      // ---- stage A: cvt + swizzled ds_write_b128 (row 128B, byte ^= ((r>>1)&7)<<4)
      #pragma unroll
      for (int j = 0; j < 4; ++j){
        int r  = rA + 8 * j;
        int sw = ((r >> 1) & 7) << 4;
        float4 f0 = fA[j][0], f1 = fA[j][1];
        bf16x8 v;
        v[0]=(__bf16)f0.x; v[1]=(__bf16)f0.y; v[2]=(__bf16)f0.z; v[3]=(__bf16)f0.w;
        v[4]=(__bf16)f1.x; v[5]=(__bf16)f1.y; v[6]=(__bf16)f1.z; v[7]=(__bf16)f1.w;
        *(bf16x8*)((char*)As + r * 128 + ((cc * 16) ^ sw)) = v;
      }
      // ---- stage B: 16 KB via global_load_lds, linear dest, inverse-swizzled source
      #pragma unroll
      for (int i = 0; i < 4; ++i){
        int L   = (w * 4 + i) * 1024 + l * 16;
        int col = L >> 7;
        int s   = L & 127;
        int sb  = kt * 128 + (s ^ (((col >> 1) & 7) << 4));
        const char* g = (const char*)Wt + (size_t)(bcol * 128 + col) * 1024 + sb;
        char* lb = (char*)Bs + (size_t)(w * 4 + i) * 1024;   // wave-uniform base
        __builtin_amdgcn_global_load_lds(GLB_AS(g), LDS_AS(lb), 16, 0, 0);
      }
      __syncthreads();                             // drains B loads + A writes

      if (kt < 7){                                 // prefetch next A tile -> regs
        const float* gk = xg + (kt + 1) * 64;
        #pragma unroll
        for (int j = 0; j < 4; ++j){
          const float* g = gk + (size_t)j * 8 * 512;
          fA[j][0] = *(const float4*)g;
          fA[j][1] = *(const float4*)(g + 4);
        }
      }

      // ---- compute: per kk: 4+4 ds_read_b128 + 16 MFMA
      #pragma unroll
      for (int kk = 0; kk < 2; ++kk){
        bf16x8 aF[4], bF[4];
        int kb = kk * 64 + (l >> 4) * 16;
        #pragma unroll
        for (int m = 0; m < 4; ++m){
          int row = wr * 64 + m * 16 + (l & 15);
          aF[m] = *(const bf16x8*)((const char*)As + row * 128 + (kb ^ (((row >> 1) & 7) << 4)));
        }
        #pragma unroll
        for (int q = 0; q < 4; ++q){
          int col = wc * 64 + q * 16 + (l & 15);
          bF[q] = *(const bf16x8*)((const char*)Bs + col * 128 + (kb ^ (((col >> 1) & 7) << 4)));
        }
        #pragma unroll
        for (int m = 0; m < 4; ++m)
          #pragma unroll
          for (int q = 0; q < 4; ++q)
            acc[m][q] = __builtin_amdgcn_mfma_f32_16x16x32_bf16(aF[m], bF[q], acc[m][q], 0, 0, 0);
      }
    }

    // epilogue: frag pairs (2p, 2p+1) = (K cols, V cols) at identical (row, src col)
    #pragma unroll
    for (int p = 0; p < 2; ++p){
      int c = (bcol * 4 + wc * 2 + p) * 16 + (l & 15);
      float bkc = bk[c], bvc = bv[c];
      float sKV = 0.f, sK = 0.f;
      #pragma unroll
      for (int m = 0; m < 4; ++m)
        #pragma unroll
        for (int r = 0; r < 4; ++r){
          float kp  = acc[m][2 * p][r] + bkc;
          float kvv = kp > 0.f ? kp + 1.f : __expf(kp);  // elu(x)+1
          sKV += kvv * (acc[m][2 * p + 1][r] + bvc);
          sK  += kvv;
        }
      sKV += __shfl_xor(sKV, 16); sKV += __shfl_xor(sKV, 32);
      sK  += __shfl_xor(sK , 16); sK  += __shfl_xor(sK , 32);
      if ((l >> 4) == 0){
        atomicAdd(&accg[n * 1024 + c],       sKV);
        atomicAdd(&accg[n * 1024 + 512 + c], sK);
      }
    }
  }

  gridbar(bar, 512);

  // ============ P2: 4 (n,o) outputs per block: dot(ov[n,:], Wo[:,o]) + gelu ============
  {
    float* ov  = (float*)As;                       // 512 floats
    float* red = ov + 512;                         // 4 floats
    int p0 = bid * 4;                              // all 4 pairs share n2
    int n2 = p0 >> 9;
    ov[tid]       = accg[n2 * 1024 + tid]       / accg[n2 * 1024 + 512 + tid];
    ov[tid + 256] = accg[n2 * 1024 + 256 + tid] / accg[n2 * 1024 + 768 + tid];
    __syncthreads();
    #pragma unroll
    for (int j = 0; j < 4; ++j){
      int o = (p0 + j) & 511;
      float s = ov[tid] * Wo[tid * 512 + o] + ov[tid + 256] * Wo[(tid + 256) * 512 + o];
      #pragma unroll
      for (int d = 1; d < 64; d <<= 1) s += __shfl_xor(s, d);
      if (l == 0) red[w] = s;
      __syncthreads();
      if (tid == 0){
        float v = red[0] + red[1] + red[2] + red[3] + bo[o];
        float u = 0.7978845608028654f * (v + 0.044715f * v * v * v);
        rowsg[p0 + j] = 0.5f * v * (1.f + tanhf(u));
      }
      __syncthreads();
    }
  }

  gridbar(bar + 1, 512);

  // ============ P3: broadcast — each block writes 8192 float4 (128 KB) ============
  {
    int n3 = bid >> 7;                             // 8192 f4 per block; n const per block
    float4* row4 = (float4*)As;
    if (tid < 128) row4[tid] = ((const float4*)(rowsg + n3 * 512))[tid];
    __syncthreads();
    float4 v = row4[tid & 127];
    float4* dst = out + (size_t)bid * 8192;
    #pragma unroll
    for (int it = 0; it < 32; ++it)
      dst[it * 256 + tid] = v;                     // 4 KB coalesced per iter
  }
}

extern "C" void kernel_launch(void* const* d_in, const int* in_sizes, int n_in,
                              void* d_out, int out_size, void* d_ws, size_t ws_size,
                              hipStream_t stream){
  const float* x  = (const float*)d_in[0];
  // d_in[1]=Wq, d_in[2]=bq  — provably irrelevant (eps/(Q*Ksum) ~ 3e-8 relative)
  const float* Wk = (const float*)d_in[3];
  const float* bk = (const float*)d_in[4];
  const float* Wv = (const float*)d_in[5];
  const float* bv = (const float*)d_in[6];
  const float* Wo = (const float*)d_in[7];
  const float* bo = (const float*)d_in[8];
  float* out = (float*)d_out;

  char* ws = (char*)d_ws;
  unsigned short* Wt = (unsigned short*)ws;            // 1 MB   bf16 [1024][512]
  float* accg = (float*)(ws + (1 << 20));              // 16 KB  [4][1024] KV|Ksum
  int*   bar  = (int*)(accg + 4096);                   // 2 barrier counters
  float* rowsg= accg + 4352;                           // 8 KB   [4][512] post-gelu

  prep_kernel <<<2048, 256, 0, stream>>>(Wk, Wv, Wt, accg);
  fused_kernel<<<512, 256, 0, stream>>>(x, Wt, bk, bv, accg, Wo, bo, bar, rowsg, (float4*)out);
}